// Round 1
// 347.532 us; speedup vs baseline: 1.0662x; 1.0662x over previous
//
#include <hip/hip_runtime.h>
#include <math.h>

// LlamaMoETopKRouter: hidden [4,4096,4096] f32, router_weight [8,4096] f32.
// Outputs (flat concat in d_out, all viewed as float):
//   [0,        32768)  expert_weights  [B,S,2]
//   [32768,    65536)  expert_indices  [B,S,2] (written as float values)
//   [65536,   196608)  router_logits   [B,S,8]
//
// R5: software-pipelined prefetch with controlled issue order.
//     Per c-iteration: (1) issue 8 weight loads (L1/L2-resident, cheap),
//     (2) issue NEXT iteration's 4 hidden float4 (nontemporal, HBM),
//     (3) FMA on CURRENT x registers. Since vmcnt completes in issue
//     order, waiting on the weight loads no longer drains the hidden
//     prefetch — next-iter HBM loads stay in flight across the entire
//     256-cycle FMA block. T=4 tokens/wave, 1024 blocks, 4 waves/SIMD
//     kept from R4 (R3 showed 2 waves/SIMD can't cover HBM latency).

#define H    4096
#define HV   (H / 4)      // float4 per row
#define NE   8
#define T    4            // tokens per wave
#define NTOK 16384        // 4*4096

typedef float vf4 __attribute__((ext_vector_type(4)));

__global__ __launch_bounds__(256, 4)
void moe_router_kernel(const float* __restrict__ hs_,
                       const float* __restrict__ rw_,
                       float* __restrict__ out) {
    const int tid  = threadIdx.x;
    const int wave = tid >> 6;
    const int lane = tid & 63;
    const int group  = blockIdx.x * 4 + wave;   // 4096 groups of T tokens
    const int token0 = group * T;

    const vf4* hs = reinterpret_cast<const vf4*>(hs_) + (size_t)token0 * HV;
    const vf4* rw = reinterpret_cast<const vf4*>(rw_);

    float acc[T][NE];
#pragma unroll
    for (int t = 0; t < T; ++t)
#pragma unroll
        for (int e = 0; e < NE; ++e) acc[t][e] = 0.0f;

    // Prologue: load c=0 hidden vectors.
    vf4 x[T], xn[T];
#pragma unroll
    for (int t = 0; t < T; ++t)
        x[t] = __builtin_nontemporal_load(&hs[(size_t)t * HV + lane]);

    for (int c = 0; c < HV; c += 64) {
        const int idx = c + lane;

        // (1) weight loads for THIS iteration — issued first so the FMA
        //     waitcnt on them does not drain the hidden prefetch below.
        vf4 w[NE];
#pragma unroll
        for (int e = 0; e < NE; ++e)
            w[e] = rw[e * HV + idx];

        // (2) prefetch NEXT iteration's hidden vectors (HBM, no reuse).
        if (c + 64 < HV) {
            const int nidx = idx + 64;
#pragma unroll
            for (int t = 0; t < T; ++t)
                xn[t] = __builtin_nontemporal_load(&hs[(size_t)t * HV + nidx]);
        }

        // (3) compute on current x.
#pragma unroll
        for (int e = 0; e < NE; ++e)
#pragma unroll
            for (int t = 0; t < T; ++t)
                acc[t][e] += x[t].x * w[e].x + x[t].y * w[e].y
                           + x[t].z * w[e].z + x[t].w * w[e].w;

        // rotate registers (compiler renames; no data movement after unroll)
#pragma unroll
        for (int t = 0; t < T; ++t) x[t] = xn[t];
    }

    // Butterfly reduce each (token, expert) partial across the 64 lanes.
#pragma unroll
    for (int t = 0; t < T; ++t)
#pragma unroll
        for (int e = 0; e < NE; ++e) {
            float v = acc[t][e];
#pragma unroll
            for (int m = 32; m > 0; m >>= 1) v += __shfl_xor(v, m, 64);
            acc[t][e] = v;
        }

    // Epilogue: lanes 0..T-1 each handle one token.
    if (lane < T) {
        float l[NE];
#pragma unroll
        for (int e = 0; e < NE; ++e) {
            float v = acc[0][e];
#pragma unroll
            for (int t = 1; t < T; ++t)
                if (lane == t) v = acc[t][e];
            l[e] = v;
        }
        const int token = token0 + lane;

        // router_logits (raw dot products)
        vf4* lg = reinterpret_cast<vf4*>(out + 4 * NTOK) + (size_t)token * 2;
        vf4 lg0 = { l[0], l[1], l[2], l[3] };
        vf4 lg1 = { l[4], l[5], l[6], l[7] };
        lg[0] = lg0;
        lg[1] = lg1;

        // top-2 (softmax is monotone in logits; ties -> lowest index, like lax.top_k)
        float v1 = l[0]; int i1 = 0;
#pragma unroll
        for (int e = 1; e < NE; ++e)
            if (l[e] > v1) { v1 = l[e]; i1 = e; }
        float v2 = -INFINITY; int i2 = 0;
#pragma unroll
        for (int e = 0; e < NE; ++e)
            if (e != i1 && l[e] > v2) { v2 = l[e]; i2 = e; }

        // renormalized top-2 softmax weights:
        // p1/(p1+p2) = 1/(1+exp(l2-l1)), exact same math as softmax->renorm.
        const float b   = expf(v2 - v1);
        const float inv = 1.0f / (1.0f + b);
        out[token * 2 + 0] = inv;
        out[token * 2 + 1] = b * inv;

        // indices, written as float values (d_out is float-typed)
        out[2 * NTOK + token * 2 + 0] = (float)i1;
        out[2 * NTOK + token * 2 + 1] = (float)i2;
    }
}

extern "C" void kernel_launch(void* const* d_in, const int* in_sizes, int n_in,
                              void* d_out, int out_size, void* d_ws, size_t ws_size,
                              hipStream_t stream) {
    const float* hs = (const float*)d_in[0];   // [4,4096,4096] f32
    const float* rw = (const float*)d_in[1];   // [8,4096] f32
    float* out = (float*)d_out;

    // 16384 tokens / (4 waves/block * 4 tokens/wave) = 1024 blocks
    dim3 grid(NTOK / (4 * T));
    dim3 block(256);
    moe_router_kernel<<<grid, block, 0, stream>>>(hs, rw, out);
}